// Round 9
// baseline (117.755 us; speedup 1.0000x reference)
//
#include <hip/hip_runtime.h>

// CRF forward (log-partition), SEQ=512, BATCH=1024, TAGS=32, fp32 in/out.
//
// R18: deep producer pipeline (T3+T4 / m201 pattern). R17's producer/consumer
// split fixed the hazard classes but used __syncthreads per chunk: the
// compiler's mandatory vmcnt(0) drain before s_barrier exposed the FULL fill
// latency inside every chunk window (measured 3250 cy/chunk vs ~500 compute).
// R18 keeps the roles (wave0 fwd consumer, wave1 bwd consumer, wave2/3
// producers) and:
//  - ring of 4 LDS chunk buffers per direction (132 KB total LDS);
//  - producers: prologue fills chunks 0-2; steady state issues FILL(k+3)
//    then waits COUNTED "s_waitcnt vmcnt(36)" (2 fills of 18 loads each
//    still in flight; never 0 until tail) before raw s_barrier -> fill
//    latency amortized over 3 chunk periods;
//  - consumers: lgkmcnt(0)+memory fence before raw s_barrier (reads of the
//    slot retired before the producer may overwrite it, ring distance 3),
//    sched_barrier(0) after each barrier (stop ds_read hoisting above the
//    barrier into the fill window - guide rule 18);
//  - barrier counts match exactly (NCH+1 per wave), one final __syncthreads
//    for the fwd/bwd junction.
// Algorithm (validated R13-R17): fwd alpha <- f_t o (E alpha) t=0..255;
// bwd u <- E^T (f_t o u) t=511..256; out = ln2*(c2f+c2b+log2(dot(u,alpha))).
// Note: the ~74us bench-vs-dispatch gap is harness fillBuffer resets
// (268 MB writes @ ~42us) - a fixed floor, not kernel time.

constexpr int SEQ = 512, BATCH = 1024, TAGS = 32;
constexpr int CH = 8;                // steps per chunk
constexpr int NCH = (SEQ / 2) / CH;  // 32 chunks per direction
constexpr int RINGN = 4;             // ring depth (chunks)
constexpr int FSLOT = CH * 512;      // feats dwords per chunk
constexpr int MSLOT = CH * 16;       // mask dwords per chunk

#define LOG2E 1.4426950408889634f
#define LN2   0.6931471805599453f

typedef __attribute__((ext_vector_type(8))) short short8;
typedef __attribute__((ext_vector_type(4))) float float4v;
union Frag8 { unsigned u[4]; short8 v; };

__device__ __forceinline__ unsigned pk_rn(float x, float y) {  // bf16 pack, x->low
  return __builtin_amdgcn_perm(__float_as_uint(y) + 0x8000u,
                               __float_as_uint(x) + 0x8000u, 0x07060302u);
}
__device__ __forceinline__ unsigned pk_tr(float x, float y) {  // trunc pack, x->low
  return __builtin_amdgcn_perm(__float_as_uint(y), __float_as_uint(x), 0x07060302u);
}

__device__ __forceinline__ void gld16(const float* g, float* l) {
  __builtin_amdgcn_global_load_lds((const __attribute__((address_space(1))) void*)g,
                                   (__attribute__((address_space(3))) void*)l, 16, 0, 0);
}
__device__ __forceinline__ void gld4(const float* g, float* l) {
  __builtin_amdgcn_global_load_lds((const __attribute__((address_space(1))) void*)g,
                                   (__attribute__((address_space(3))) void*)l, 4, 0, 0);
}

// ---------------- producer: stream chunks into the LDS ring ----------------
template <bool FWD>
__device__ __forceinline__ void produce(
    const float* __restrict__ feats, const float* __restrict__ maskp,
    float* __restrict__ FFd, float* __restrict__ MMd, int b0, int lane) {
  // feats: 2 gld16 per step (batches 0-7, 8-15). LDS dword d of a step slot
  // holds feats[t][b0+(d>>5)][(d&31) ^ (((d>>5)&7)<<2)] (pre-swizzled src).
  const int bs = lane >> 3;
  const int tg = 4 * ((lane & 7) ^ (bs & 7));
  const size_t t0 = FWD ? 0 : (size_t)(SEQ - 1);
  const float* gF0 = feats + t0 * BATCH * TAGS + (size_t)(b0 + bs) * TAGS + tg;
  const float* gF8 = gF0 + 8 * TAGS;
  const float* gM0 = maskp +
      (FWD ? (size_t)(lane >> 4) : (size_t)(SEQ - 1 - (lane >> 4))) * BATCH +
      b0 + (lane & 15);
  const ptrdiff_t fstep = FWD ? (ptrdiff_t)(BATCH * TAGS) : -(ptrdiff_t)(BATCH * TAGS);
  const ptrdiff_t mstep = FWD ? (ptrdiff_t)BATCH : -(ptrdiff_t)BATCH;

  auto FILL = [&](int k) {  // 18 vmcnt events per FILL
    float* fb = FFd + (k & (RINGN - 1)) * FSLOT;
    float* mb = MMd + (k & (RINGN - 1)) * MSLOT;
#pragma unroll
    for (int j = 0; j < CH; ++j) {
      const ptrdiff_t o = (ptrdiff_t)(CH * k + j) * fstep;
      gld16(gF0 + o, fb + j * 512);
      gld16(gF8 + o, fb + j * 512 + 256);
    }
    gld4(gM0 + (ptrdiff_t)(CH * k) * mstep, mb);
    gld4(gM0 + (ptrdiff_t)(CH * k + 4) * mstep, mb + 64);
  };

  FILL(0); FILL(1); FILL(2);                          // 54 in flight
  asm volatile("s_waitcnt vmcnt(36)" ::: "memory");   // chunk 0 landed
  __builtin_amdgcn_s_barrier();                       // B0
  for (int k = 0; k < NCH; ++k) {
    if (k < NCH - 3) {
      FILL(k + 3);                                    // 54 in flight again
      asm volatile("s_waitcnt vmcnt(36)" ::: "memory");  // chunk k+1 landed
    } else if (k == NCH - 3) {
      asm volatile("s_waitcnt vmcnt(18)" ::: "memory");  // chunk k+1 landed
    } else if (k == NCH - 2) {
      asm volatile("s_waitcnt vmcnt(0)" ::: "memory");   // last chunk landed
    }
    __builtin_amdgcn_s_barrier();                     // B(k+1)
  }
  __syncthreads();  // junction barrier (match consumers)
}

// ---------------- consumer: run one direction's chain ----------------
template <bool FWD>
__device__ __forceinline__ void consume(
    const float* __restrict__ trans, float* __restrict__ out,
    const float* __restrict__ FFd, const float* __restrict__ MMd,
    float* __restrict__ vbuf, float* __restrict__ c2buf, int b0, int lane) {
  const int s = lane & 15, q = lane >> 4;

  // sigma-permuted E fragments (A-operand layout: row=l&15, k in sig order
  // {4q..4q+3, 16+4q..16+4q+3} - verified R9-R17).
  int sig[8];
#pragma unroll
  for (int i = 0; i < 8; ++i) sig[i] = (i < 4) ? (4 * q + i) : (16 + 4 * q + (i - 4));
  Frag8 e0, e1;  // FWD: E rows (D=E*B). BWD: E^T rows.
#pragma unroll
  for (int p = 0; p < 4; ++p) {
    if (FWD) {
      e0.u[p] = pk_rn(__builtin_amdgcn_exp2f(trans[s * TAGS + sig[2 * p]] * LOG2E),
                      __builtin_amdgcn_exp2f(trans[s * TAGS + sig[2 * p + 1]] * LOG2E));
      e1.u[p] = pk_rn(__builtin_amdgcn_exp2f(trans[(16 + s) * TAGS + sig[2 * p]] * LOG2E),
                      __builtin_amdgcn_exp2f(trans[(16 + s) * TAGS + sig[2 * p + 1]] * LOG2E));
    } else {
      e0.u[p] = pk_rn(__builtin_amdgcn_exp2f(trans[sig[2 * p] * TAGS + s] * LOG2E),
                      __builtin_amdgcn_exp2f(trans[sig[2 * p + 1] * TAGS + s] * LOG2E));
      e1.u[p] = pk_rn(__builtin_amdgcn_exp2f(trans[sig[2 * p] * TAGS + 16 + s] * LOG2E),
                      __builtin_amdgcn_exp2f(trans[sig[2 * p + 1] * TAGS + 16 + s] * LOG2E));
    }
  }

  // state: a[i] = vec[j][b=s], j = sig-mapped.
  float a[8];
#pragma unroll
  for (int i = 0; i < 8; ++i) {
    if (FWD) a[i] = (q == 3 && i == 6) ? 1.0f : 0.0f;  // alpha0 = e_30
    else a[i] = __builtin_amdgcn_exp2f(
        trans[31 * TAGS + ((i < 4) ? (4 * q + i) : (16 + 4 * q + (i - 4)))] * LOG2E);
  }
  Frag8 Bf;
  Bf.u[0] = pk_tr(a[0], a[1]); Bf.u[1] = pk_tr(a[2], a[3]);
  Bf.u[2] = pk_tr(a[4], a[5]); Bf.u[3] = pk_tr(a[6], a[7]);
  float c2 = 0.f;
  const float4v zerov = {0.f, 0.f, 0.f, 0.f};

  // LDS read offsets (dwords within a step slot); 2-way max bank aliasing.
  const int off0 = s * 32 + ((q ^ (s & 7)) << 2);
  const int off1 = s * 32 + (((q + 4) ^ (s & 7)) << 2);

  __builtin_amdgcn_s_barrier();  // B0: chunk 0 ready
  __builtin_amdgcn_sched_barrier(0);
  for (int k = 0; k < NCH; ++k) {
    const float* fb = FFd + (k & (RINGN - 1)) * FSLOT;
    const float* mb = MMd + (k & (RINGN - 1)) * MSLOT;
#pragma unroll
    for (int j = 0; j < CH; ++j) {
      const float4v r0 = *(const float4v*)(fb + j * 512 + off0);
      const float4v r1 = *(const float4v*)(fb + j * 512 + off1);
      const float mval = mb[j * 16 + s];
      float4v Fc0, Fc1;
#pragma unroll
      for (int i = 0; i < 4; ++i) {
        Fc0[i] = __builtin_amdgcn_exp2f(r0[i] * LOG2E);
        Fc1[i] = __builtin_amdgcn_exp2f(r1[i] * LOG2E);
      }
      const bool mv = (mval != 0.0f);
      if (FWD) {
        // alpha' = F o (E alpha): D rows 4q+p == next B k-slots, same lane.
        const float4v D0 = __builtin_amdgcn_mfma_f32_16x16x32_bf16(e0.v, Bf.v, zerov, 0, 0, 0);
        const float4v D1 = __builtin_amdgcn_mfma_f32_16x16x32_bf16(e1.v, Bf.v, zerov, 0, 0, 0);
#pragma unroll
        for (int i = 0; i < 4; ++i) {
          a[i] = mv ? D0[i] * Fc0[i] : a[i];
          a[4 + i] = mv ? D1[i] * Fc1[i] : a[4 + i];
        }
      } else {
        // u' = E^T (F o u): mul before pack/MFMA.
        float tb[8];
#pragma unroll
        for (int i = 0; i < 4; ++i) { tb[i] = a[i] * Fc0[i]; tb[4 + i] = a[4 + i] * Fc1[i]; }
        Frag8 Bp;
        Bp.u[0] = pk_tr(tb[0], tb[1]); Bp.u[1] = pk_tr(tb[2], tb[3]);
        Bp.u[2] = pk_tr(tb[4], tb[5]); Bp.u[3] = pk_tr(tb[6], tb[7]);
        const float4v D0 = __builtin_amdgcn_mfma_f32_16x16x32_bf16(e0.v, Bp.v, zerov, 0, 0, 0);
        const float4v D1 = __builtin_amdgcn_mfma_f32_16x16x32_bf16(e1.v, Bp.v, zerov, 0, 0, 0);
#pragma unroll
        for (int i = 0; i < 4; ++i) {
          a[i] = mv ? D0[i] : a[i];
          a[4 + i] = mv ? D1[i] : a[4 + i];
        }
      }
      if (j == CH - 1) {  // renorm once per chunk (growth < 2^110)
        float mx = fmaxf(fmaxf(fmaxf(a[0], a[1]), fmaxf(a[2], a[3])),
                         fmaxf(fmaxf(a[4], a[5]), fmaxf(a[6], a[7])));
        mx = fmaxf(mx, __shfl_xor(mx, 16, 64));
        mx = fmaxf(mx, __shfl_xor(mx, 32, 64));
        const int ex = (int)((__float_as_uint(mx) >> 23) & 0xFFu) - 127;
        const float scl = __uint_as_float((unsigned)(127 - ex) << 23);  // exact 2^-ex
#pragma unroll
        for (int i = 0; i < 8; ++i) a[i] *= scl;
        c2 += (float)ex;
      }
      if (FWD) {
        Bf.u[0] = pk_tr(a[0], a[1]); Bf.u[1] = pk_tr(a[2], a[3]);
        Bf.u[2] = pk_tr(a[4], a[5]); Bf.u[3] = pk_tr(a[6], a[7]);
      }
    }
    // reads of slot k retired before the producer may overwrite it (dist 3)
    asm volatile("s_waitcnt lgkmcnt(0)" ::: "memory");
    __builtin_amdgcn_s_barrier();  // B(k+1)
    __builtin_amdgcn_sched_barrier(0);
  }

  // ---- junction: out[b] = ln2 * (c2f + c2b + log2(dot(u, alpha)))
  if (!FWD) {
    float4v lo = {a[0], a[1], a[2], a[3]}, hi = {a[4], a[5], a[6], a[7]};
    *(float4v*)(vbuf + lane * 8) = lo;
    *(float4v*)(vbuf + lane * 8 + 4) = hi;
    if (lane < 16) c2buf[lane] = c2;
  }
  __syncthreads();  // junction barrier
  if (FWD) {
    const float4v v0 = *(const float4v*)(vbuf + lane * 8);
    const float4v v1 = *(const float4v*)(vbuf + lane * 8 + 4);
    float dot = a[0] * v0[0] + a[1] * v0[1] + a[2] * v0[2] + a[3] * v0[3] +
                a[4] * v1[0] + a[5] * v1[1] + a[6] * v1[2] + a[7] * v1[3];
    dot += __shfl_xor(dot, 16, 64);
    dot += __shfl_xor(dot, 32, 64);
    if (lane < 16)
      out[b0 + lane] = LN2 * (c2 + c2buf[lane] + __builtin_amdgcn_logf(dot));
  }
}

extern "C" __global__ void __launch_bounds__(256, 1) crf_scan(
    const float* __restrict__ feats, const float* __restrict__ mask,
    const float* __restrict__ trans, float* __restrict__ out) {
  __shared__ float FF[2][RINGN][FSLOT];  // 128 KB
  __shared__ float MM[2][RINGN][MSLOT];  // 4 KB
  __shared__ float vbuf[512];            // 2 KB
  __shared__ float c2buf[16];
  const int wid = threadIdx.x >> 6;
  const int lane = threadIdx.x & 63;
  const int b0 = blockIdx.x * 16;  // 16 batches per block

  if (wid == 0)
    consume<true>(trans, out, &FF[0][0][0], &MM[0][0][0], vbuf, c2buf, b0, lane);
  else if (wid == 1)
    consume<false>(trans, out, &FF[1][0][0], &MM[1][0][0], vbuf, c2buf, b0, lane);
  else if (wid == 2)
    produce<true>(feats, mask, &FF[0][0][0], &MM[0][0][0], b0, lane);
  else
    produce<false>(feats, mask, &FF[1][0][0], &MM[1][0][0], b0, lane);
}

extern "C" void kernel_launch(void* const* d_in, const int* in_sizes, int n_in,
                              void* d_out, int out_size, void* d_ws, size_t ws_size,
                              hipStream_t stream) {
  const float* feats = (const float*)d_in[0];
  const float* mask  = (const float*)d_in[1];
  const float* trans = (const float*)d_in[2];
  float* out = (float*)d_out;
  hipLaunchKernelGGL(crf_scan, dim3(BATCH / 16), dim3(256), 0, stream,
                     feats, mask, trans, out);
}